// Round 1
// 547.898 us; speedup vs baseline: 1.0177x; 1.0177x over previous
//
#include <hip/hip_runtime.h>

#define NN 16
#define CIN 256
#define COUT 256
#define LL 300
#define VV 25
#define VP 28                  // padded Aw row (112 B, 16B-aligned)
#define PP 3
#define KS 9
#define KK 768                 // GEMM K = P*CIN
#define MM (NN*LL*VV)          // 120000 GEMM rows
#define MPAD 120064            // 938 * 128
#define MBLK 938
#define XCDS 8
#define NLP 150                // l-pair blocks per n (LL/2)
#define LPX 19                 // ceil(150/8) l-pairs per XCD-slice
#define GWID (2*MBLK)          // 1876 gemm work items
#define GPX 235                // ceil(1876/8)

typedef float floatx4 __attribute__((ext_vector_type(4)));
typedef short short8 __attribute__((ext_vector_type(8)));

__device__ __forceinline__ unsigned short f2bf(float f) {
    unsigned u = __builtin_bit_cast(unsigned, f);
    u += 0x7fff + ((u >> 16) & 1);          // round-to-nearest-even
    return (unsigned short)(u >> 16);
}
__device__ __forceinline__ float bf2f(unsigned short h) {
    unsigned u = ((unsigned)h) << 16;
    return __builtin_bit_cast(float, u);
}
__device__ __forceinline__ void gl2lds16(const void* g, void* l) {
    __builtin_amdgcn_global_load_lds(
        (const __attribute__((address_space(1))) void*)g,
        (__attribute__((address_space(3))) void*)l, 16, 0, 0);
}

// ---------------- prep: W2T (bf16, N x K), b2t[w][c] (transposed), pad ----
__global__ __launch_bounds__(256) void k_prep(
    const float* __restrict__ A, const float* __restrict__ conv_w,
    const float* __restrict__ conv_b, const float* __restrict__ ei,
    unsigned short* __restrict__ w2t, float* __restrict__ b2t,
    unsigned short* __restrict__ xa)
{
    const int t = blockIdx.x * 256 + threadIdx.x;
    const int nthr = gridDim.x * 256;
    for (int idx = t; idx < COUT * KK; idx += nthr) {
        int c = idx / KK, k = idx % KK, p = k >> 8, ci = k & 255;
        w2t[idx] = f2bf(conv_w[(p * COUT + c) * CIN + ci]);
    }
    for (int idx = t; idx < COUT * VV; idx += nthr) {
        int c = idx / VV, w = idx % VV;
        float s = 0.f;
        for (int p = 0; p < PP; ++p) {
            float cs = 0.f;
            for (int v = 0; v < VV; ++v) {
                int a = (p * VV + v) * VV + w;
                cs += A[a] * ei[a];
            }
            s += conv_b[p * COUT + c] * cs;
        }
        b2t[w * COUT + c] = s;              // TRANSPOSED: flat z-layout w*256+c
    }
    for (int idx = t; idx < (MPAD - MM) * KK; idx += nthr)
        xa[(size_t)MM * KK + idx] = 0;
}

// ---------------- pre-aggregation: xa[(n,l,w)][(p,ci)] = sum_v x*Aw --------
__global__ __launch_bounds__(256) void k_agg(
    const float* __restrict__ x, const float* __restrict__ A,
    const float* __restrict__ ei, unsigned short* __restrict__ xa)
{
    __shared__ float AwL[PP * VV * VP];   // [p][v][w], rows padded to 28
    const int l = blockIdx.x, n = blockIdx.y, t = threadIdx.x;  // t = ci
    for (int idx = t; idx < PP * VV * VV; idx += 256) {
        int pv = idx / VV, w = idx % VV;
        AwL[pv * VP + w] = A[idx] * ei[idx];
    }
    __syncthreads();

    float xv[VV];
    const float* xp = x + ((size_t)(n * CIN + t) * LL + l) * VV;
    #pragma unroll
    for (int v = 0; v < VV; ++v) xv[v] = xp[v];

    const size_t mrow = (size_t)(n * LL + l) * VV;
    #pragma unroll
    for (int p = 0; p < PP; ++p) {
        float acc[VV];
        #pragma unroll
        for (int w = 0; w < VV; ++w) acc[w] = 0.f;
        #pragma unroll
        for (int v = 0; v < VV; ++v) {
            const float xvv = xv[v];
            const float* ar = &AwL[(p * VV + v) * VP];
            #pragma unroll
            for (int wq = 0; wq < 24; wq += 4) {
                const float4 f = *(const float4*)(ar + wq);
                acc[wq + 0] += xvv * f.x; acc[wq + 1] += xvv * f.y;
                acc[wq + 2] += xvv * f.z; acc[wq + 3] += xvv * f.w;
            }
            acc[24] += xvv * ar[24];
        }
        #pragma unroll
        for (int w = 0; w < VV; ++w)
            xa[(mrow + w) * KK + p * CIN + t] = f2bf(acc[w]);
    }
}

// ---------------- GEMM: z[m][c] = xa[m][:] . w2t[c][:]  (bf16 MFMA) --------
// XCD-aware pairing: each XCD gets consecutive work-ids; the (m,c0)/(m,c1)
// pair is adjacent within one XCD -> A-panel (196 KB) read once from HBM.
__global__ __launch_bounds__(256) void k_gemm(
    const unsigned short* __restrict__ xa,
    const unsigned short* __restrict__ w2t,
    unsigned short* __restrict__ z)
{
    __shared__ __align__(16) unsigned short As[128 * 32];
    __shared__ __align__(16) unsigned short Bs[128 * 32];
    const int bid = blockIdx.x;
    const int g = bid & (XCDS - 1), sidx = bid >> 3;
    const int wid = g * GPX + sidx;
    if (wid >= GWID) return;
    const int m0 = (wid >> 1) * 128, c0 = (wid & 1) * 128;
    const int t = threadIdx.x, wv = t >> 6, ln = t & 63;

    floatx4 acc[4][4];
    #pragma unroll
    for (int i = 0; i < 4; ++i)
        #pragma unroll
        for (int j = 0; j < 4; ++j)
            acc[i][j] = (floatx4){0.f, 0.f, 0.f, 0.f};

    const int srow = wv * 32 + (ln >> 2);
    const int scol = (ln & 3) * 8;
    const int mw = (wv >> 1) * 64, nw = (wv & 1) * 64;
    const int frow = ln & 15, fcol = (ln >> 4) * 8;

    for (int kt = 0; kt < KK / 32; ++kt) {
        const int k0 = kt * 32;
        __syncthreads();
        gl2lds16(xa  + (size_t)(m0 + srow)      * KK + k0 + scol, &As[(wv * 32) * 32]);
        gl2lds16(xa  + (size_t)(m0 + srow + 16) * KK + k0 + scol, &As[(wv * 32 + 16) * 32]);
        gl2lds16(w2t + (size_t)(c0 + srow)      * KK + k0 + scol, &Bs[(wv * 32) * 32]);
        gl2lds16(w2t + (size_t)(c0 + srow + 16) * KK + k0 + scol, &Bs[(wv * 32 + 16) * 32]);
        __syncthreads();

        short8 af[4], bf[4];
        #pragma unroll
        for (int i = 0; i < 4; ++i)
            af[i] = *(const short8*)&As[(mw + i * 16 + frow) * 32 + fcol];
        #pragma unroll
        for (int j = 0; j < 4; ++j)
            bf[j] = *(const short8*)&Bs[(nw + j * 16 + frow) * 32 + fcol];
        #pragma unroll
        for (int i = 0; i < 4; ++i)
            #pragma unroll
            for (int j = 0; j < 4; ++j)
                acc[i][j] = __builtin_amdgcn_mfma_f32_16x16x32_bf16(af[i], bf[j], acc[i][j], 0, 0, 0);
    }

    const int q = ln >> 4, cL = ln & 15;
    #pragma unroll
    for (int i = 0; i < 4; ++i) {
        #pragma unroll
        for (int j = 0; j < 4; ++j) {
            #pragma unroll
            for (int r = 0; r < 4; ++r) {
                const int m = m0 + mw + i * 16 + q * 4 + r;
                const int c = c0 + nw + j * 16 + cL;
                if (m < MM) z[(size_t)m * COUT + c] = f2bf(acc[i][j][r]);
            }
        }
    }
}

// ------- 9-tap temporal sum + bias + LayerNorm + relu + residual + relu ----
// Block = (n, l-pair). Phase A: coalesced short8 z reads in z-layout, fp32
// tap sums for both l's staged in LDS + LN stats. Phase B: LDS transpose,
// aligned float2 residual/out writes. XCD g owns contiguous l-range.
__global__ __launch_bounds__(256) void k_ln(
    const unsigned short* __restrict__ z, const float* __restrict__ x,
    const float* __restrict__ b2t, const float* __restrict__ gamma,
    const float* __restrict__ beta, float* __restrict__ out)
{
    __shared__ __align__(16) float ylds[2][VV * COUT];   // 51200 B
    __shared__ float red[4][4];
    __shared__ float stats[4];

    const int b = blockIdx.x;
    const int g = b & (XCDS - 1);
    const int r = b >> 3;
    const int li = r % LPX;
    const int n  = r / LPX;
    const int lp = g * LPX + li;
    if (lp >= NLP) return;
    const int l0 = lp * 2;
    const int t = threadIdx.x;

    float s10 = 0.f, s20 = 0.f, s11 = 0.f, s21 = 0.f;
    const size_t zrow0 = (size_t)(n * LL) * (VV * COUT);

    // ---- Phase A: tap sums, 800 short8 slots over 256 threads ----
    #pragma unroll
    for (int i = 0; i < 4; ++i) {
        const int vs = t + 256 * i;
        if (i < 3 || t < 32) {          // vs < 800
            float f[10][8];
            #pragma unroll
            for (int j = 0; j < 10; ++j) {
                const int lr = l0 - 8 + j;
                if (lr >= 0) {
                    const short8 rv = *(const short8*)(z + zrow0 + (size_t)lr * (VV * COUT) + vs * 8);
                    #pragma unroll
                    for (int k = 0; k < 8; ++k) f[j][k] = bf2f((unsigned short)rv[k]);
                } else {
                    #pragma unroll
                    for (int k = 0; k < 8; ++k) f[j][k] = 0.f;
                }
            }
            const float cnt0 = (float)(((l0     < 8) ? l0     : 8) + 1);
            const float cnt1 = (float)(((l0 + 1 < 8) ? l0 + 1 : 8) + 1);
            const float4 ba = *(const float4*)(b2t + vs * 8);
            const float4 bb = *(const float4*)(b2t + vs * 8 + 4);
            const float bv[8] = {ba.x, ba.y, ba.z, ba.w, bb.x, bb.y, bb.z, bb.w};
            float y0[8], y1[8];
            #pragma unroll
            for (int k = 0; k < 8; ++k) {
                float smid = f[1][k];
                #pragma unroll
                for (int j = 2; j < 9; ++j) smid += f[j][k];
                const float a = smid + f[0][k] + cnt0 * bv[k];
                const float c = smid + f[9][k] + cnt1 * bv[k];
                y0[k] = a; y1[k] = c;
                s10 += a; s20 += a * a;
                s11 += c; s21 += c * c;
            }
            *(float4*)&ylds[0][vs * 8]     = (float4){y0[0], y0[1], y0[2], y0[3]};
            *(float4*)&ylds[0][vs * 8 + 4] = (float4){y0[4], y0[5], y0[6], y0[7]};
            *(float4*)&ylds[1][vs * 8]     = (float4){y1[0], y1[1], y1[2], y1[3]};
            *(float4*)&ylds[1][vs * 8 + 4] = (float4){y1[4], y1[5], y1[6], y1[7]};
        }
    }

    // ---- LN stats (two rows) ----
    #pragma unroll
    for (int off = 32; off; off >>= 1) {
        s10 += __shfl_down(s10, off);
        s20 += __shfl_down(s20, off);
        s11 += __shfl_down(s11, off);
        s21 += __shfl_down(s21, off);
    }
    const int wid = t >> 6, lane = t & 63;
    if (lane == 0) { red[wid][0] = s10; red[wid][1] = s20; red[wid][2] = s11; red[wid][3] = s21; }
    __syncthreads();
    if (t == 0) {
        float S1 = 0.f, S2 = 0.f, T1 = 0.f, T2 = 0.f;
        #pragma unroll
        for (int w2 = 0; w2 < 4; ++w2) { S1 += red[w2][0]; S2 += red[w2][1]; T1 += red[w2][2]; T2 += red[w2][3]; }
        const float inv = 1.f / (COUT * VV);
        float mu = S1 * inv, var = S2 * inv - mu * mu;
        stats[0] = mu; stats[1] = rsqrtf(var + 1e-5f);
        mu = T1 * inv; var = T2 * inv - mu * mu;
        stats[2] = mu; stats[3] = rsqrtf(var + 1e-5f);
    }
    __syncthreads();

    // ---- Phase B: normalize + transpose via LDS + residual, c = t ----
    const float mu0 = stats[0], rsd0 = stats[1], mu1 = stats[2], rsd1 = stats[3];
    const int c = t;
    const float* gp = gamma + c * VV;
    const float* bp = beta  + c * VV;
    const float* xp = x   + ((size_t)(n * CIN  + c) * (LL * VV)) + l0 * VV;
    float*       op = out + ((size_t)(n * COUT + c) * (LL * VV)) + l0 * VV;
    float val[2 * VV];
    #pragma unroll
    for (int w = 0; w < VV; ++w) {
        const float gw = gp[w], bw = bp[w];
        const float v0 = (ylds[0][w * COUT + c] - mu0) * rsd0 * gw + bw;
        const float v1 = (ylds[1][w * COUT + c] - mu1) * rsd1 * gw + bw;
        val[w]      = fmaxf(v0, 0.f);
        val[VV + w] = fmaxf(v1, 0.f);
    }
    #pragma unroll
    for (int k = 0; k < VV; ++k) {
        const float2 xv = *(const float2*)(xp + 2 * k);
        float2 o;
        o.x = fmaxf(val[2 * k]     + xv.x, 0.f);
        o.y = fmaxf(val[2 * k + 1] + xv.y, 0.f);
        *(float2*)(op + 2 * k) = o;
    }
}

extern "C" void kernel_launch(void* const* d_in, const int* in_sizes, int n_in,
                              void* d_out, int out_size, void* d_ws, size_t ws_size,
                              hipStream_t stream) {
    const float* x      = (const float*)d_in[0];
    const float* A      = (const float*)d_in[1];
    const float* conv_w = (const float*)d_in[2];
    const float* conv_b = (const float*)d_in[3];
    const float* gamma  = (const float*)d_in[4];
    const float* beta   = (const float*)d_in[5];
    const float* ei     = (const float*)d_in[6];
    float* out = (float*)d_out;

    char* ws = (char*)d_ws;
    unsigned short* xa  = (unsigned short*)ws;                    // 184,418,304 B
    unsigned short* z   = (unsigned short*)(ws + 184418304);      //  61,472,768 B
    unsigned short* w2t = (unsigned short*)(ws + 245891072);      //     393,216 B
    float*          b2  = (float*)(ws + 246284288);               //      25,600 B

    k_prep<<<64, 256, 0, stream>>>(A, conv_w, conv_b, ei, w2t, b2, xa);
    k_agg<<<dim3(LL, NN), 256, 0, stream>>>(x, A, ei, xa);
    k_gemm<<<XCDS * GPX, 256, 0, stream>>>(xa, w2t, z);
    k_ln<<<XCDS * LPX * NN, 256, 0, stream>>>(z, x, b2, gamma, beta, out);
}

// Round 2
// 520.770 us; speedup vs baseline: 1.0707x; 1.0521x over previous
//
#include <hip/hip_runtime.h>

#define NN 16
#define CIN 256
#define COUT 256
#define LL 300
#define VV 25
#define VP 28                  // padded Aw row (112 B, 16B-aligned)
#define PP 3
#define KS 9
#define KK 768                 // GEMM K = P*CIN
#define MM (NN*LL*VV)          // 120000 GEMM rows
#define MPAD 120064            // 938 * 128
#define MBLK 938
#define XCDS 8
#define NLP 150                // l-pair blocks per n (LL/2)
#define LPX 19                 // ceil(150/8) l-pairs per XCD-slice
#define GWID (2*MBLK)          // 1876 gemm work items
#define GPX 235                // ceil(1876/8)

typedef float floatx4 __attribute__((ext_vector_type(4)));
typedef short short8 __attribute__((ext_vector_type(8)));

__device__ __forceinline__ unsigned short f2bf(float f) {
    unsigned u = __builtin_bit_cast(unsigned, f);
    u += 0x7fff + ((u >> 16) & 1);          // round-to-nearest-even
    return (unsigned short)(u >> 16);
}
__device__ __forceinline__ float bf2f(unsigned short h) {
    unsigned u = ((unsigned)h) << 16;
    return __builtin_bit_cast(float, u);
}
__device__ __forceinline__ void gl2lds16(const void* g, void* l) {
    __builtin_amdgcn_global_load_lds(
        (const __attribute__((address_space(1))) void*)g,
        (__attribute__((address_space(3))) void*)l, 16, 0, 0);
}
__device__ __forceinline__ int div25(int x) {   // x < 65536
    return (x * 5243) >> 17;
}

// ---------------- prep: W2T (bf16, N x K), b2t[w][c] (transposed), pad ----
__global__ __launch_bounds__(256) void k_prep(
    const float* __restrict__ A, const float* __restrict__ conv_w,
    const float* __restrict__ conv_b, const float* __restrict__ ei,
    unsigned short* __restrict__ w2t, float* __restrict__ b2t,
    unsigned short* __restrict__ xa)
{
    const int t = blockIdx.x * 256 + threadIdx.x;
    const int nthr = gridDim.x * 256;
    for (int idx = t; idx < COUT * KK; idx += nthr) {
        int c = idx / KK, k = idx % KK, p = k >> 8, ci = k & 255;
        w2t[idx] = f2bf(conv_w[(p * COUT + c) * CIN + ci]);
    }
    for (int idx = t; idx < COUT * VV; idx += nthr) {
        int c = idx / VV, w = idx % VV;
        float s = 0.f;
        for (int p = 0; p < PP; ++p) {
            float cs = 0.f;
            for (int v = 0; v < VV; ++v) {
                int a = (p * VV + v) * VV + w;
                cs += A[a] * ei[a];
            }
            s += conv_b[p * COUT + c] * cs;
        }
        b2t[w * COUT + c] = s;              // TRANSPOSED: flat z-layout w*256+c
    }
    for (int idx = t; idx < (MPAD - MM) * KK; idx += nthr)
        xa[(size_t)MM * KK + idx] = 0;
}

// ---------------- pre-aggregation: xa[(n,l,w)][(p,ci)] = sum_v x*Aw --------
// x[n,:,l,:] staged through LDS with flattened coalesced loads (the direct
// per-thread pattern is a 64-line-per-instruction gather at 30000B stride).
__global__ __launch_bounds__(256) void k_agg(
    const float* __restrict__ x, const float* __restrict__ A,
    const float* __restrict__ ei, unsigned short* __restrict__ xa)
{
    __shared__ float AwL[PP * VV * VP];   // [p][v][w], rows padded to 28
    __shared__ float xL[CIN * VV];        // [ci][v], 25600 B
    const int l = blockIdx.x, n = blockIdx.y, t = threadIdx.x;  // t = ci
    for (int idx = t; idx < PP * VV * VV; idx += 256) {
        int pv = idx / VV, w = idx % VV;
        AwL[pv * VP + w] = A[idx] * ei[idx];
    }
    const size_t base_nl = (size_t)n * (CIN * LL * VV) + (size_t)l * VV;
    #pragma unroll
    for (int k = 0; k < VV; ++k) {                 // 6400 = 25 * 256
        const int idx = k * 256 + t;               // = ci*25 + v
        const int ci = div25(idx);
        const int v = idx - ci * 25;
        xL[idx] = x[base_nl + (size_t)ci * (LL * VV) + v];
    }
    __syncthreads();

    float xv[VV];
    #pragma unroll
    for (int v = 0; v < VV; ++v) xv[v] = xL[t * VV + v];

    const size_t mrow = (size_t)(n * LL + l) * VV;
    #pragma unroll
    for (int p = 0; p < PP; ++p) {
        float acc[VV];
        #pragma unroll
        for (int w = 0; w < VV; ++w) acc[w] = 0.f;
        #pragma unroll
        for (int v = 0; v < VV; ++v) {
            const float xvv = xv[v];
            const float* ar = &AwL[(p * VV + v) * VP];
            #pragma unroll
            for (int wq = 0; wq < 24; wq += 4) {
                const float4 f = *(const float4*)(ar + wq);
                acc[wq + 0] += xvv * f.x; acc[wq + 1] += xvv * f.y;
                acc[wq + 2] += xvv * f.z; acc[wq + 3] += xvv * f.w;
            }
            acc[24] += xvv * ar[24];
        }
        #pragma unroll
        for (int w = 0; w < VV; ++w)
            xa[(mrow + w) * KK + p * CIN + t] = f2bf(acc[w]);
    }
}

// ---------------- GEMM: z[m][c] = xa[m][:] . w2t[c][:]  (bf16 MFMA) --------
// XCD-aware pairing: each XCD gets consecutive work-ids; the (m,c0)/(m,c1)
// pair is adjacent within one XCD -> A-panel (196 KB) read once from HBM.
__global__ __launch_bounds__(256) void k_gemm(
    const unsigned short* __restrict__ xa,
    const unsigned short* __restrict__ w2t,
    unsigned short* __restrict__ z)
{
    __shared__ __align__(16) unsigned short As[128 * 32];
    __shared__ __align__(16) unsigned short Bs[128 * 32];
    const int bid = blockIdx.x;
    const int g = bid & (XCDS - 1), sidx = bid >> 3;
    const int wid = g * GPX + sidx;
    if (wid >= GWID) return;
    const int m0 = (wid >> 1) * 128, c0 = (wid & 1) * 128;
    const int t = threadIdx.x, wv = t >> 6, ln = t & 63;

    floatx4 acc[4][4];
    #pragma unroll
    for (int i = 0; i < 4; ++i)
        #pragma unroll
        for (int j = 0; j < 4; ++j)
            acc[i][j] = (floatx4){0.f, 0.f, 0.f, 0.f};

    const int srow = wv * 32 + (ln >> 2);
    const int scol = (ln & 3) * 8;
    const int mw = (wv >> 1) * 64, nw = (wv & 1) * 64;
    const int frow = ln & 15, fcol = (ln >> 4) * 8;

    for (int kt = 0; kt < KK / 32; ++kt) {
        const int k0 = kt * 32;
        __syncthreads();
        gl2lds16(xa  + (size_t)(m0 + srow)      * KK + k0 + scol, &As[(wv * 32) * 32]);
        gl2lds16(xa  + (size_t)(m0 + srow + 16) * KK + k0 + scol, &As[(wv * 32 + 16) * 32]);
        gl2lds16(w2t + (size_t)(c0 + srow)      * KK + k0 + scol, &Bs[(wv * 32) * 32]);
        gl2lds16(w2t + (size_t)(c0 + srow + 16) * KK + k0 + scol, &Bs[(wv * 32 + 16) * 32]);
        __syncthreads();

        short8 af[4], bf[4];
        #pragma unroll
        for (int i = 0; i < 4; ++i)
            af[i] = *(const short8*)&As[(mw + i * 16 + frow) * 32 + fcol];
        #pragma unroll
        for (int j = 0; j < 4; ++j)
            bf[j] = *(const short8*)&Bs[(nw + j * 16 + frow) * 32 + fcol];
        #pragma unroll
        for (int i = 0; i < 4; ++i)
            #pragma unroll
            for (int j = 0; j < 4; ++j)
                acc[i][j] = __builtin_amdgcn_mfma_f32_16x16x32_bf16(af[i], bf[j], acc[i][j], 0, 0, 0);
    }

    const int q = ln >> 4, cL = ln & 15;
    #pragma unroll
    for (int i = 0; i < 4; ++i) {
        #pragma unroll
        for (int j = 0; j < 4; ++j) {
            #pragma unroll
            for (int r = 0; r < 4; ++r) {
                const int m = m0 + mw + i * 16 + q * 4 + r;
                const int c = c0 + nw + j * 16 + cL;
                if (m < MM) z[(size_t)m * COUT + c] = f2bf(acc[i][j][r]);
            }
        }
    }
}

// ------- 9-tap temporal sum + bias + LayerNorm + relu + residual + relu ----
// Phase A: coalesced short8 z reads (e-layout), fp32 tap sums -> LDS + stats.
// Phase B: thread=c normalizes (conflict-free LDS reads), rewrites SAME LDS
//          buffer in c-major layout.
// Phase C: flattened-index walk -> LDS linear reads + near-contiguous
//          global x/gamma/beta loads and out stores (~8 lines/instr vs 64).
__global__ __launch_bounds__(256) void k_ln(
    const unsigned short* __restrict__ z, const float* __restrict__ x,
    const float* __restrict__ b2t, const float* __restrict__ gamma,
    const float* __restrict__ beta, float* __restrict__ out)
{
    __shared__ __align__(16) float Y[2 * VV * COUT];     // 51200 B
    __shared__ float red[4][4];
    __shared__ float stats[4];

    const int b = blockIdx.x;
    const int g = b & (XCDS - 1);
    const int r = b >> 3;
    const int li = r % LPX;
    const int n  = r / LPX;
    const int lp = g * LPX + li;
    if (lp >= NLP) return;
    const int l0 = lp * 2;
    const int t = threadIdx.x;

    float s10 = 0.f, s20 = 0.f, s11 = 0.f, s21 = 0.f;
    const size_t zrow0 = (size_t)(n * LL) * (VV * COUT);

    // ---- Phase A: tap sums, 800 short8 slots over 256 threads ----
    #pragma unroll
    for (int i = 0; i < 4; ++i) {
        const int vs = t + 256 * i;
        if (i < 3 || t < 32) {          // vs < 800
            float f[10][8];
            #pragma unroll
            for (int j = 0; j < 10; ++j) {
                const int lr = l0 - 8 + j;
                if (lr >= 0) {
                    const short8 rv = *(const short8*)(z + zrow0 + (size_t)lr * (VV * COUT) + vs * 8);
                    #pragma unroll
                    for (int k = 0; k < 8; ++k) f[j][k] = bf2f((unsigned short)rv[k]);
                } else {
                    #pragma unroll
                    for (int k = 0; k < 8; ++k) f[j][k] = 0.f;
                }
            }
            const float cnt0 = (float)(((l0     < 8) ? l0     : 8) + 1);
            const float cnt1 = (float)(((l0 + 1 < 8) ? l0 + 1 : 8) + 1);
            const float4 ba = *(const float4*)(b2t + vs * 8);
            const float4 bb = *(const float4*)(b2t + vs * 8 + 4);
            const float bv[8] = {ba.x, ba.y, ba.z, ba.w, bb.x, bb.y, bb.z, bb.w};
            float y0[8], y1[8];
            #pragma unroll
            for (int k = 0; k < 8; ++k) {
                float smid = f[1][k];
                #pragma unroll
                for (int j = 2; j < 9; ++j) smid += f[j][k];
                const float a = smid + f[0][k] + cnt0 * bv[k];
                const float c = smid + f[9][k] + cnt1 * bv[k];
                y0[k] = a; y1[k] = c;
                s10 += a; s20 += a * a;
                s11 += c; s21 += c * c;
            }
            *(float4*)&Y[vs * 8]                 = (float4){y0[0], y0[1], y0[2], y0[3]};
            *(float4*)&Y[vs * 8 + 4]             = (float4){y0[4], y0[5], y0[6], y0[7]};
            *(float4*)&Y[VV * COUT + vs * 8]     = (float4){y1[0], y1[1], y1[2], y1[3]};
            *(float4*)&Y[VV * COUT + vs * 8 + 4] = (float4){y1[4], y1[5], y1[6], y1[7]};
        }
    }

    // ---- LN stats (two rows) ----
    #pragma unroll
    for (int off = 32; off; off >>= 1) {
        s10 += __shfl_down(s10, off);
        s20 += __shfl_down(s20, off);
        s11 += __shfl_down(s11, off);
        s21 += __shfl_down(s21, off);
    }
    const int wid = t >> 6, lane = t & 63;
    if (lane == 0) { red[wid][0] = s10; red[wid][1] = s20; red[wid][2] = s11; red[wid][3] = s21; }
    __syncthreads();
    if (t == 0) {
        float S1 = 0.f, S2 = 0.f, T1 = 0.f, T2 = 0.f;
        #pragma unroll
        for (int w2 = 0; w2 < 4; ++w2) { S1 += red[w2][0]; S2 += red[w2][1]; T1 += red[w2][2]; T2 += red[w2][3]; }
        const float inv = 1.f / (COUT * VV);
        float mu = S1 * inv, var = S2 * inv - mu * mu;
        stats[0] = mu; stats[1] = rsqrtf(var + 1e-5f);
        mu = T1 * inv; var = T2 * inv - mu * mu;
        stats[2] = mu; stats[3] = rsqrtf(var + 1e-5f);
    }
    __syncthreads();

    // ---- Phase B: normalize (thread = c, conflict-free reads), then
    //      rewrite Y in c-major [c][f] layout (f = dl*25 + v) ----
    const float mu0 = stats[0], rsd0 = stats[1], mu1 = stats[2], rsd1 = stats[3];
    const int c = t;
    float val[50];
    #pragma unroll
    for (int f = 0; f < 50; ++f) {
        const int dl = (f >= VV) ? 1 : 0;
        const int v = f - dl * VV;
        const float y = Y[dl * (VV * COUT) + v * COUT + c];
        val[f] = (y - (dl ? mu1 : mu0)) * (dl ? rsd1 : rsd0);
    }
    __syncthreads();
    #pragma unroll
    for (int f = 0; f < 50; f += 2)
        *(float2*)&Y[c * 50 + f] = (float2){val[f], val[f + 1]};
    __syncthreads();

    // ---- Phase C: coalesced gamma/beta/x/out walk ----
    const size_t base_n = (size_t)n * COUT * (LL * VV) + (size_t)l0 * VV;
    #pragma unroll
    for (int k = 0; k < 25; ++k) {
        const int fi = k * 256 + t;              // float2 index in [0, 6400)
        const int c2 = div25(fi);
        const int j  = fi - c2 * 25;
        const int f0 = 2 * j;                    // f in [0, 50)
        const int f1 = f0 + 1;
        const int va = (f0 >= VV) ? (f0 - VV) : f0;
        const int vb = (f1 >= VV) ? (f1 - VV) : f1;
        const float2 yv = *(const float2*)&Y[fi * 2];
        const float ga = gamma[c2 * VV + va], gb2 = gamma[c2 * VV + vb];
        const float bb2 = beta[c2 * VV + va],  bc = beta[c2 * VV + vb];
        const size_t goff = base_n + (size_t)c2 * (LL * VV) + f0;
        const float2 xv = *(const float2*)(x + goff);
        float2 o;
        o.x = fmaxf(fmaxf(yv.x * ga  + bb2, 0.f) + xv.x, 0.f);
        o.y = fmaxf(fmaxf(yv.y * gb2 + bc,  0.f) + xv.y, 0.f);
        *(float2*)(out + goff) = o;
    }
}

extern "C" void kernel_launch(void* const* d_in, const int* in_sizes, int n_in,
                              void* d_out, int out_size, void* d_ws, size_t ws_size,
                              hipStream_t stream) {
    const float* x      = (const float*)d_in[0];
    const float* A      = (const float*)d_in[1];
    const float* conv_w = (const float*)d_in[2];
    const float* conv_b = (const float*)d_in[3];
    const float* gamma  = (const float*)d_in[4];
    const float* beta   = (const float*)d_in[5];
    const float* ei     = (const float*)d_in[6];
    float* out = (float*)d_out;

    char* ws = (char*)d_ws;
    unsigned short* xa  = (unsigned short*)ws;                    // 184,418,304 B
    unsigned short* z   = (unsigned short*)(ws + 184418304);      //  61,472,768 B
    unsigned short* w2t = (unsigned short*)(ws + 245891072);      //     393,216 B
    float*          b2  = (float*)(ws + 246284288);               //      25,600 B

    k_prep<<<64, 256, 0, stream>>>(A, conv_w, conv_b, ei, w2t, b2, xa);
    k_agg<<<dim3(LL, NN), 256, 0, stream>>>(x, A, ei, xa);
    k_gemm<<<XCDS * GPX, 256, 0, stream>>>(xa, w2t, z);
    k_ln<<<XCDS * LPX * NN, 256, 0, stream>>>(z, x, b2, gamma, beta, out);
}

// Round 4
// 508.669 us; speedup vs baseline: 1.0962x; 1.0238x over previous
//
#include <hip/hip_runtime.h>

#define NN 16
#define CIN 256
#define COUT 256
#define LL 300
#define VV 25
#define VP 28                  // padded Aw row (112 B, 16B-aligned)
#define PP 3
#define KS 9
#define KK 768                 // GEMM K = P*CIN
#define MM (NN*LL*VV)          // 120000 GEMM rows
#define MPAD 120064            // 938 * 128
#define MBLK 938
#define XCDS 8
#define LX 38                  // ceil(300/8) l's per XCD-slice
#define GWID (2*MBLK)          // 1876 gemm work items
#define GPX 235                // ceil(1876/8)

typedef float floatx4 __attribute__((ext_vector_type(4)));
typedef short short8 __attribute__((ext_vector_type(8)));

__device__ __forceinline__ unsigned short f2bf(float f) {
    unsigned u = __builtin_bit_cast(unsigned, f);
    u += 0x7fff + ((u >> 16) & 1);          // round-to-nearest-even
    return (unsigned short)(u >> 16);
}
__device__ __forceinline__ float bf2f(unsigned short h) {
    unsigned u = ((unsigned)h) << 16;
    return __builtin_bit_cast(float, u);
}
__device__ __forceinline__ void gl2lds16(const void* g, void* l) {
    __builtin_amdgcn_global_load_lds(
        (const __attribute__((address_space(1))) void*)g,
        (__attribute__((address_space(3))) void*)l, 16, 0, 0);
}
__device__ __forceinline__ int div25(int x) {   // x < 65536
    return (x * 5243) >> 17;
}

// ---------------- prep: W2T (bf16, N x K), b2t[w][c] (transposed), pad ----
__global__ __launch_bounds__(256) void k_prep(
    const float* __restrict__ A, const float* __restrict__ conv_w,
    const float* __restrict__ conv_b, const float* __restrict__ ei,
    unsigned short* __restrict__ w2t, float* __restrict__ b2t,
    unsigned short* __restrict__ xa)
{
    const int t = blockIdx.x * 256 + threadIdx.x;
    const int nthr = gridDim.x * 256;
    for (int idx = t; idx < COUT * KK; idx += nthr) {
        int c = idx / KK, k = idx % KK, p = k >> 8, ci = k & 255;
        w2t[idx] = f2bf(conv_w[(p * COUT + c) * CIN + ci]);
    }
    for (int idx = t; idx < COUT * VV; idx += nthr) {
        int c = idx / VV, w = idx % VV;
        float s = 0.f;
        for (int p = 0; p < PP; ++p) {
            float cs = 0.f;
            for (int v = 0; v < VV; ++v) {
                int a = (p * VV + v) * VV + w;
                cs += A[a] * ei[a];
            }
            s += conv_b[p * COUT + c] * cs;
        }
        b2t[w * COUT + c] = s;              // TRANSPOSED: flat z-layout w*256+c
    }
    for (int idx = t; idx < (MPAD - MM) * KK; idx += nthr)
        xa[(size_t)MM * KK + idx] = 0;
}

// ---------------- pre-aggregation: xa[(n,l,w)][(p,ci)] = sum_v x*Aw --------
// x[n,:,l,:] staged through LDS with flattened coalesced loads (the direct
// per-thread pattern is a 64-line-per-instruction gather at 30000B stride).
__global__ __launch_bounds__(256) void k_agg(
    const float* __restrict__ x, const float* __restrict__ A,
    const float* __restrict__ ei, unsigned short* __restrict__ xa)
{
    __shared__ float AwL[PP * VV * VP];   // [p][v][w], rows padded to 28
    __shared__ float xL[CIN * VV];        // [ci][v], 25600 B
    const int l = blockIdx.x, n = blockIdx.y, t = threadIdx.x;  // t = ci
    for (int idx = t; idx < PP * VV * VV; idx += 256) {
        int pv = idx / VV, w = idx % VV;
        AwL[pv * VP + w] = A[idx] * ei[idx];
    }
    const size_t base_nl = (size_t)n * (CIN * LL * VV) + (size_t)l * VV;
    #pragma unroll
    for (int k = 0; k < VV; ++k) {                 // 6400 = 25 * 256
        const int idx = k * 256 + t;               // = ci*25 + v
        const int ci = div25(idx);
        const int v = idx - ci * 25;
        xL[idx] = x[base_nl + (size_t)ci * (LL * VV) + v];
    }
    __syncthreads();

    float xv[VV];
    #pragma unroll
    for (int v = 0; v < VV; ++v) xv[v] = xL[t * VV + v];

    const size_t mrow = (size_t)(n * LL + l) * VV;
    #pragma unroll
    for (int p = 0; p < PP; ++p) {
        float acc[VV];
        #pragma unroll
        for (int w = 0; w < VV; ++w) acc[w] = 0.f;
        #pragma unroll
        for (int v = 0; v < VV; ++v) {
            const float xvv = xv[v];
            const float* ar = &AwL[(p * VV + v) * VP];
            #pragma unroll
            for (int wq = 0; wq < 24; wq += 4) {
                const float4 f = *(const float4*)(ar + wq);
                acc[wq + 0] += xvv * f.x; acc[wq + 1] += xvv * f.y;
                acc[wq + 2] += xvv * f.z; acc[wq + 3] += xvv * f.w;
            }
            acc[24] += xvv * ar[24];
        }
        #pragma unroll
        for (int w = 0; w < VV; ++w)
            xa[(mrow + w) * KK + p * CIN + t] = f2bf(acc[w]);
    }
}

// ---------------- GEMM: z[m][c] = xa[m][:] . w2t[c][:]  (bf16 MFMA) --------
// XCD-aware pairing: each XCD gets consecutive work-ids; the (m,c0)/(m,c1)
// pair is adjacent within one XCD -> A-panel (196 KB) read once from HBM.
__global__ __launch_bounds__(256) void k_gemm(
    const unsigned short* __restrict__ xa,
    const unsigned short* __restrict__ w2t,
    unsigned short* __restrict__ z)
{
    __shared__ __align__(16) unsigned short As[128 * 32];
    __shared__ __align__(16) unsigned short Bs[128 * 32];
    const int bid = blockIdx.x;
    const int g = bid & (XCDS - 1), sidx = bid >> 3;
    const int wid = g * GPX + sidx;
    if (wid >= GWID) return;
    const int m0 = (wid >> 1) * 128, c0 = (wid & 1) * 128;
    const int t = threadIdx.x, wv = t >> 6, ln = t & 63;

    floatx4 acc[4][4];
    #pragma unroll
    for (int i = 0; i < 4; ++i)
        #pragma unroll
        for (int j = 0; j < 4; ++j)
            acc[i][j] = (floatx4){0.f, 0.f, 0.f, 0.f};

    const int srow = wv * 32 + (ln >> 2);
    const int scol = (ln & 3) * 8;
    const int mw = (wv >> 1) * 64, nw = (wv & 1) * 64;
    const int frow = ln & 15, fcol = (ln >> 4) * 8;

    for (int kt = 0; kt < KK / 32; ++kt) {
        const int k0 = kt * 32;
        __syncthreads();
        gl2lds16(xa  + (size_t)(m0 + srow)      * KK + k0 + scol, &As[(wv * 32) * 32]);
        gl2lds16(xa  + (size_t)(m0 + srow + 16) * KK + k0 + scol, &As[(wv * 32 + 16) * 32]);
        gl2lds16(w2t + (size_t)(c0 + srow)      * KK + k0 + scol, &Bs[(wv * 32) * 32]);
        gl2lds16(w2t + (size_t)(c0 + srow + 16) * KK + k0 + scol, &Bs[(wv * 32 + 16) * 32]);
        __syncthreads();

        short8 af[4], bf[4];
        #pragma unroll
        for (int i = 0; i < 4; ++i)
            af[i] = *(const short8*)&As[(mw + i * 16 + frow) * 32 + fcol];
        #pragma unroll
        for (int j = 0; j < 4; ++j)
            bf[j] = *(const short8*)&Bs[(nw + j * 16 + frow) * 32 + fcol];
        #pragma unroll
        for (int i = 0; i < 4; ++i)
            #pragma unroll
            for (int j = 0; j < 4; ++j)
                acc[i][j] = __builtin_amdgcn_mfma_f32_16x16x32_bf16(af[i], bf[j], acc[i][j], 0, 0, 0);
    }

    const int q = ln >> 4, cL = ln & 15;
    #pragma unroll
    for (int i = 0; i < 4; ++i) {
        #pragma unroll
        for (int j = 0; j < 4; ++j) {
            #pragma unroll
            for (int r = 0; r < 4; ++r) {
                const int m = m0 + mw + i * 16 + q * 4 + r;
                const int c = c0 + nw + j * 16 + cL;
                if (m < MM) z[(size_t)m * COUT + c] = f2bf(acc[i][j][r]);
            }
        }
    }
}

// ------- 9-tap temporal sum + bias + LayerNorm + relu + residual + relu ----
// One l per block: LDS 25.7 KB (was 51.7) -> occupancy no longer LDS-capped.
// Phase A: coalesced short8 z reads (9 taps into regs, then accumulate),
//          fp32 tap sums -> LDS (e-major) + LN stats.
// Phase B: thread=c normalizes + gamma/beta + relu, rewrites Y c-major.
// Phase C: batch 25 x loads into regs, then LDS linear read + residual.
// XCD g owns contiguous l-range -> 9-row z window stays L2-hot.
__global__ __launch_bounds__(256, 4) void k_ln(
    const unsigned short* __restrict__ z, const float* __restrict__ x,
    const float* __restrict__ b2t, const float* __restrict__ gamma,
    const float* __restrict__ beta, float* __restrict__ out)
{
    __shared__ __align__(16) float Y[VV * COUT];     // 25600 B
    __shared__ float red[4][2];
    __shared__ float stats[2];

    const int b = blockIdx.x;
    const int g = b & (XCDS - 1);
    const int r = b >> 3;
    const int mi = r % LX;
    const int n  = r / LX;
    const int l  = g * LX + mi;
    if (l >= LL) return;
    const int t = threadIdx.x;

    const size_t zrow0 = (size_t)(n * LL) * (VV * COUT);
    const float cnt = (float)(((l < 8) ? l : 8) + 1);
    float s1 = 0.f, s2 = 0.f;

    // ---- Phase A: 800 short8 slots over 256 threads (3 full + tail 32) ----
    #pragma unroll
    for (int i = 0; i < 4; ++i) {
        const int vs = t + 256 * i;
        if (i < 3 || t < 32) {          // vs < 800
            short8 rv[9];
            #pragma unroll
            for (int j = 0; j < 9; ++j) {
                const int lr = l - 8 + j;
                if (lr >= 0)
                    rv[j] = *(const short8*)(z + zrow0 + (size_t)lr * (VV * COUT) + vs * 8);
                else
                    rv[j] = (short8){0, 0, 0, 0, 0, 0, 0, 0};
            }
            const float4 ba = *(const float4*)(b2t + vs * 8);
            const float4 bb = *(const float4*)(b2t + vs * 8 + 4);
            const float bv[8] = {ba.x, ba.y, ba.z, ba.w, bb.x, bb.y, bb.z, bb.w};
            float y[8];
            #pragma unroll
            for (int k = 0; k < 8; ++k) {
                float a = cnt * bv[k];
                #pragma unroll
                for (int j = 0; j < 9; ++j)
                    a += bf2f((unsigned short)rv[j][k]);   // lr<0 lanes add 0.0
                y[k] = a;
                s1 += a; s2 += a * a;
            }
            *(float4*)&Y[vs * 8]     = (float4){y[0], y[1], y[2], y[3]};
            *(float4*)&Y[vs * 8 + 4] = (float4){y[4], y[5], y[6], y[7]};
        }
    }

    // ---- LN stats ----
    #pragma unroll
    for (int off = 32; off; off >>= 1) {
        s1 += __shfl_down(s1, off);
        s2 += __shfl_down(s2, off);
    }
    const int wid = t >> 6, lane = t & 63;
    if (lane == 0) { red[wid][0] = s1; red[wid][1] = s2; }
    __syncthreads();
    if (t == 0) {
        float S1 = 0.f, S2 = 0.f;
        #pragma unroll
        for (int w2 = 0; w2 < 4; ++w2) { S1 += red[w2][0]; S2 += red[w2][1]; }
        const float inv = 1.f / (COUT * VV);
        const float mu = S1 * inv;
        const float var = S2 * inv - mu * mu;
        stats[0] = mu; stats[1] = rsqrtf(var + 1e-5f);
    }
    __syncthreads();

    // ---- Phase B: thread=c, normalize + gamma/beta + relu; rewrite c-major --
    const float mu = stats[0], rsd = stats[1];
    const int c = t;
    const float* gp = gamma + c * VV;
    const float* bp = beta  + c * VV;
    float val[VV];
    #pragma unroll
    for (int v = 0; v < VV; ++v)
        val[v] = fmaxf((Y[v * COUT + c] - mu) * rsd * gp[v] + bp[v], 0.f);
    __syncthreads();
    #pragma unroll
    for (int v = 0; v < VV; ++v)
        Y[c * VV + v] = val[v];                 // stride-25: gcd(25,32)=1, no conflict
    __syncthreads();

    // ---- Phase C: batch x loads, then residual + relu + store ----
    const size_t base = (size_t)n * COUT * (LL * VV) + (size_t)l * VV;
    float xr[VV];
    #pragma unroll
    for (int k = 0; k < VV; ++k) {
        const int fi = k * 256 + t;             // element (c2, v)
        const int c2 = div25(fi);
        const int v  = fi - c2 * VV;
        xr[k] = x[base + (size_t)c2 * (LL * VV) + v];
    }
    #pragma unroll
    for (int k = 0; k < VV; ++k) {
        const int fi = k * 256 + t;
        const int c2 = div25(fi);
        const int v  = fi - c2 * VV;
        out[base + (size_t)c2 * (LL * VV) + v] = fmaxf(Y[fi] + xr[k], 0.f);
    }
}

extern "C" void kernel_launch(void* const* d_in, const int* in_sizes, int n_in,
                              void* d_out, int out_size, void* d_ws, size_t ws_size,
                              hipStream_t stream) {
    const float* x      = (const float*)d_in[0];
    const float* A      = (const float*)d_in[1];
    const float* conv_w = (const float*)d_in[2];
    const float* conv_b = (const float*)d_in[3];
    const float* gamma  = (const float*)d_in[4];
    const float* beta   = (const float*)d_in[5];
    const float* ei     = (const float*)d_in[6];
    float* out = (float*)d_out;

    char* ws = (char*)d_ws;
    unsigned short* xa  = (unsigned short*)ws;                    // 184,418,304 B
    unsigned short* z   = (unsigned short*)(ws + 184418304);      //  61,472,768 B
    unsigned short* w2t = (unsigned short*)(ws + 245891072);      //     393,216 B
    float*          b2  = (float*)(ws + 246284288);               //      25,600 B

    k_prep<<<64, 256, 0, stream>>>(A, conv_w, conv_b, ei, w2t, b2, xa);
    k_agg<<<dim3(LL, NN), 256, 0, stream>>>(x, A, ei, xa);
    k_gemm<<<XCDS * GPX, 256, 0, stream>>>(xa, w2t, z);
    k_ln<<<XCDS * LX * NN, 256, 0, stream>>>(z, x, b2, gamma, beta, out);
}